// Round 1
// baseline (156.549 us; speedup 1.0000x reference)
//
#include <hip/hip_runtime.h>
#include <math.h>

// ---------------------------------------------------------------------------
// Cosine_PredictingModule v10.
//   cat@W1 = heads@W1a + tails@W1b + cos*W1[128]  (per-node precompute).
//   Node record (one 128-B line): [64 B fp8 hn | 64 B fp8 P(+b1 cust)].
//   K1 node_fused: v8 (all global traffic coalesced).
//   K2 edge_mlp v10: 8 lanes/edge -> ONE 128-B request per record (was two
//      64-B requests, often double-missing L1). 6 batches of 8 edges per
//      wave (48 edges/wave), all 12 gathers issued before compute ->
//      12 KB in flight per wave. Lanes 0-3 of each edge-group do the cosine
//      partial, lanes 4-7 the MLP partial; cos crosses via shfl_xor(.,4).
// ---------------------------------------------------------------------------

typedef __attribute__((ext_vector_type(8))) short bf16x8;
typedef __attribute__((ext_vector_type(4))) float f32x4;
typedef __attribute__((ext_vector_type(2))) float float2_t;
typedef __attribute__((ext_vector_type(8))) unsigned short ushort8_t;
typedef __attribute__((ext_vector_type(4))) float float4_t;
typedef __attribute__((ext_vector_type(4))) unsigned int uint4_t;
typedef __attribute__((ext_vector_type(2))) unsigned int uint2_t;

#define T_STRIDE 72   // A-tile LDS stride (ushorts)
#define P_STRIDE 72   // acc-transpose LDS stride (ushorts)

__device__ __forceinline__ float bf2f(unsigned short u) {
    return __uint_as_float(((unsigned int)u) << 16);
}
__device__ __forceinline__ unsigned short f2bf(float f) {
    unsigned int x = __float_as_uint(f);
    return (unsigned short)((x + 0x7fffu + ((x >> 16) & 1u)) >> 16);
}

// K0: W1frag[half][nt][ks][lane][j] =
//   bf16(W1[half*64 + ks*32 + (lane>>4)*8 + j][nt*16 + (lane&15)])
__global__ __launch_bounds__(256) void prep_w1(
    const float* __restrict__ W1, unsigned short* __restrict__ frag)
{
    int idx = blockIdx.x * 256 + threadIdx.x;
    if (idx >= 2 * 4 * 2 * 64 * 8) return;
    int j    = idx & 7;
    int lane = (idx >> 3) & 63;
    int ks   = (idx >> 9) & 1;
    int nt   = (idx >> 10) & 3;
    int half = (idx >> 12) & 1;
    int k   = ks * 32 + (lane >> 4) * 8 + j;
    int col = nt * 16 + (lane & 15);
    frag[idx] = f2bf(W1[(half * 64 + k) * 64 + col]);
}

// K1 v8: 64 nodes/block, all global traffic coalesced.
__global__ __launch_bounds__(256) void node_fused(
    const float* __restrict__ hc, const float* __restrict__ hp,
    const unsigned short* __restrict__ w1frag, const float* __restrict__ b1,
    unsigned char* __restrict__ recC, unsigned char* __restrict__ recP,
    int nC, int nP, int blocksC)
{
    __shared__ unsigned short tileA[64 * T_STRIDE];
    __shared__ unsigned short tile2[64 * P_STRIDE];
    __shared__ unsigned char  recs[64 * 128];

    int b = blockIdx.x;
    const float* h; unsigned char* rec; int n, half;
    if (b < blocksC) { h = hc; rec = recC; n = nC; half = 0; }
    else { b -= blocksC; h = hp; rec = recP; n = nP; half = 1; }

    int node0 = b * 64;
    int nloc  = min(64, n - node0);
    int t     = threadIdx.x;
    int nl    = t >> 2, q = t & 3;
    int wave  = t >> 6, lane = t & 63;
    int m = lane & 15, quad = lane >> 4;

    if (nl < nloc) {
        const float* srcp = h + (long)(node0 + nl) * 64 + q * 16;
        float4_t v[4];
#pragma unroll
        for (int i = 0; i < 4; i++)
            v[i] = *reinterpret_cast<const float4_t*>(srcp + i * 4);

        float ss = 0.f;
#pragma unroll
        for (int i = 0; i < 4; i++)
#pragma unroll
            for (int j = 0; j < 4; j++) ss += v[i][j] * v[i][j];
        ss += __shfl_xor(ss, 1);
        ss += __shfl_xor(ss, 2);
        float inv = 1.f / fmaxf(sqrtf(ss), 1e-12f);

        ushort8_t u[2];
#pragma unroll
        for (int i = 0; i < 16; i++) u[i >> 3][i & 7] = f2bf(v[i >> 2][i & 3]);
        *reinterpret_cast<ushort8_t*>(&tileA[nl * T_STRIDE + q * 16])     = u[0];
        *reinterpret_cast<ushort8_t*>(&tileA[nl * T_STRIDE + q * 16 + 8]) = u[1];

        uint4_t u8;
#pragma unroll
        for (int i = 0; i < 4; i++) {
            unsigned int d = __builtin_amdgcn_cvt_pk_fp8_f32(
                v[i][0] * inv, v[i][1] * inv, 0, false);
            d = __builtin_amdgcn_cvt_pk_fp8_f32(
                v[i][2] * inv, v[i][3] * inv, d, true);
            u8[i] = d;
        }
        *reinterpret_cast<uint4_t*>(&recs[nl * 128 + q * 16]) = u8;
    }
    __syncthreads();

    if (wave * 16 < nloc) {
        bf16x8 a[2];
#pragma unroll
        for (int ks = 0; ks < 2; ks++)
            a[ks] = *reinterpret_cast<const bf16x8*>(
                &tileA[(wave * 16 + m) * T_STRIDE + ks * 32 + quad * 8]);

        f32x4 acc[4];
#pragma unroll
        for (int nt = 0; nt < 4; nt++) acc[nt] = (f32x4){0.f, 0.f, 0.f, 0.f};
#pragma unroll
        for (int nt = 0; nt < 4; nt++)
#pragma unroll
            for (int ks = 0; ks < 2; ks++) {
                bf16x8 bf = *reinterpret_cast<const bf16x8*>(
                    &w1frag[(((half * 4 + nt) * 2 + ks) * 64 + lane) * 8]);
                acc[nt] = __builtin_amdgcn_mfma_f32_16x16x32_bf16(
                    a[ks], bf, acc[nt], 0, 0, 0);
            }
        if (half == 0) {
#pragma unroll
            for (int nt = 0; nt < 4; nt++) {
                float bb = b1[nt * 16 + m];
#pragma unroll
                for (int r = 0; r < 4; r++) acc[nt][r] += bb;
            }
        }
#pragma unroll
        for (int nt = 0; nt < 4; nt++)
#pragma unroll
            for (int r = 0; r < 4; r++)
                tile2[(wave * 16 + quad * 4 + r) * P_STRIDE + nt * 16 + m]
                    = f2bf(acc[nt][r]);
    }
    __syncthreads();

    if (nl < nloc) {
        ushort8_t p0 = *reinterpret_cast<ushort8_t*>(&tile2[nl * P_STRIDE + q * 16]);
        ushort8_t p1 = *reinterpret_cast<ushort8_t*>(&tile2[nl * P_STRIDE + q * 16 + 8]);
        float v[16];
#pragma unroll
        for (int i = 0; i < 8; i++) { v[i] = bf2f(p0[i]); v[i + 8] = bf2f(p1[i]); }
        uint4_t u;
#pragma unroll
        for (int i = 0; i < 4; i++) {
            unsigned int d = __builtin_amdgcn_cvt_pk_fp8_f32(
                v[i * 4 + 0], v[i * 4 + 1], 0, false);
            d = __builtin_amdgcn_cvt_pk_fp8_f32(
                v[i * 4 + 2], v[i * 4 + 3], d, true);
            u[i] = d;
        }
        *reinterpret_cast<uint4_t*>(&recs[nl * 128 + 64 + q * 16]) = u;
    }
    __syncthreads();

    if (t * 32 < nloc * 128) {
        uint4_t r0 = *reinterpret_cast<uint4_t*>(&recs[t * 32]);
        uint4_t r1 = *reinterpret_cast<uint4_t*>(&recs[t * 32 + 16]);
        unsigned char* dstp = rec + (long)node0 * 128 + t * 32;
        *reinterpret_cast<uint4_t*>(dstp)      = r0;
        *reinterpret_cast<uint4_t*>(dstp + 16) = r1;
    }
}

// K2 v10: 8 lanes/edge -> one 128-B request per record. 6 batches of
// 8 edges per wave (48 edges/wave); all 12 gathers issued before compute.
// Lanes g=0..3 hold hn bytes (cosine), lanes g=4..7 hold P bytes (MLP).
#define NB 6
__global__ __launch_bounds__(256, 4) void edge_mlp(
    const unsigned char* __restrict__ recC, const unsigned char* __restrict__ recP,
    const int* __restrict__ src, const int* __restrict__ dst,
    const float* __restrict__ W1, const float* __restrict__ W2,
    const float* __restrict__ b2, float* __restrict__ out, int nE)
{
    int lane = threadIdx.x & 63;
    int sub  = lane >> 3;      // edge slot within batch (0..7)
    int g    = lane & 7;       // 16-B chunk within the two records
    int wid  = (blockIdx.x * 256 + threadIdx.x) >> 6;
    int base = wid * (NB * 8);

    int ed[NB]; int sI[NB], tI[NB]; bool vd[NB];
#pragma unroll
    for (int b = 0; b < NB; b++) {
        ed[b] = base + b * 8 + sub;
        vd[b] = ed[b] < nE;
        sI[b] = vd[b] ? src[ed[b]] : 0;
        tI[b] = vd[b] ? dst[ed[b]] : 0;
    }

    // Issue all 12 record gathers up front (one full 128-B line each:
    // 8 lanes x 16 B contiguous).
    uint4_t cs[NB], ct[NB];
#pragma unroll
    for (int b = 0; b < NB; b++) {
        cs[b] = *reinterpret_cast<const uint4_t*>(
            recC + (long)sI[b] * 128 + g * 16);
        ct[b] = *reinterpret_cast<const uint4_t*>(
            recP + (long)tI[b] * 128 + g * 16);
    }

    // L1-hot parameter loads (used by MLP lanes g>=4; harmless elsewhere).
    int d0p = (g & 3) * 16;
    float4_t w1v[4], w2v[4];
#pragma unroll
    for (int i = 0; i < 4; i++) {
        w1v[i] = *reinterpret_cast<const float4_t*>(W1 + 128 * 64 + d0p + i * 4);
        w2v[i] = *reinterpret_cast<const float4_t*>(W2 + d0p + i * 4);
    }
    float b2v = b2[0];

#pragma unroll
    for (int b = 0; b < NB; b++) {
        uint4_t a = cs[b];
        uint4_t c = ct[b];

        // Pass 1: 4-lane-group dot. For g<4 this is the cosine partial
        // (hn_c . hn_p over 16 dims/lane); for g>=4 it's discarded.
        float dot = 0.f;
#pragma unroll
        for (int w = 0; w < 4; w++) {
            float2_t alo = __builtin_amdgcn_cvt_pk_f32_fp8((int)a[w], false);
            float2_t ahi = __builtin_amdgcn_cvt_pk_f32_fp8((int)a[w], true);
            float2_t blo = __builtin_amdgcn_cvt_pk_f32_fp8((int)c[w], false);
            float2_t bhi = __builtin_amdgcn_cvt_pk_f32_fp8((int)c[w], true);
            dot += alo[0] * blo[0] + alo[1] * blo[1] + ahi[0] * bhi[0] + ahi[1] * bhi[1];
        }
        dot += __shfl_xor(dot, 1);
        dot += __shfl_xor(dot, 2);
        float ov   = __shfl_xor(dot, 4);          // cross hn-half <-> P-half
        float cosv = (g & 4) ? ov : dot;          // denom folded (~1)

        // Pass 2: MLP partial on lanes g>=4 (16 hidden dims/lane).
        float p = 0.f;
        if (g & 4) {
#pragma unroll
            for (int w = 0; w < 4; w++) {
                float2_t clo = __builtin_amdgcn_cvt_pk_f32_fp8((int)a[w], false);
                float2_t chi = __builtin_amdgcn_cvt_pk_f32_fp8((int)a[w], true);
                float2_t dlo = __builtin_amdgcn_cvt_pk_f32_fp8((int)c[w], false);
                float2_t dhi = __builtin_amdgcn_cvt_pk_f32_fp8((int)c[w], true);
                float pcv[4] = {clo[0], clo[1], chi[0], chi[1]};
                float ppv[4] = {dlo[0], dlo[1], dhi[0], dhi[1]};
#pragma unroll
                for (int j = 0; j < 4; j++) {
                    float x = pcv[j] + ppv[j] + cosv * w1v[w][j];  // b1 folded
                    x = fmaxf(x, 0.f);
                    p += x * w2v[w][j];
                }
            }
        }
        p += __shfl_xor(p, 1);
        p += __shfl_xor(p, 2);
        p += __shfl_xor(p, 4);   // lanes 0-3 contributed 0; now all have total

        if (vd[b] && g == 0)
            out[ed[b]] = 1.f / (1.f + expf(-(p + b2v)));
    }
}

extern "C" void kernel_launch(void* const* d_in, const int* in_sizes, int n_in,
                              void* d_out, int out_size, void* d_ws, size_t ws_size,
                              hipStream_t stream) {
    const float* h_c = (const float*)d_in[0];
    const float* h_p = (const float*)d_in[1];
    const int*   src = (const int*)d_in[2];
    const int*   dst = (const int*)d_in[3];
    const float* W1  = (const float*)d_in[4];
    const float* b1  = (const float*)d_in[5];
    const float* W2  = (const float*)d_in[6];
    const float* b2  = (const float*)d_in[7];
    float* out = (float*)d_out;

    int nC = in_sizes[0] / 64;
    int nP = in_sizes[1] / 64;
    int nE = in_sizes[2];

    char* ws = (char*)d_ws;
    size_t off = 0;
    auto carve = [&](size_t bytes) {
        void* p = ws + off;
        off = (off + bytes + 255) & ~(size_t)255;
        return p;
    };
    unsigned char* recC = (unsigned char*)carve((size_t)nC * 128);
    unsigned char* recP = (unsigned char*)carve((size_t)nP * 128);
    unsigned short* w1f = (unsigned short*)carve((size_t)16384 * 2);

    prep_w1<<<64, 256, 0, stream>>>(W1, w1f);

    int blocksC = (nC + 63) / 64, blocksP = (nP + 63) / 64;
    node_fused<<<blocksC + blocksP, 256, 0, stream>>>(
        h_c, h_p, w1f, b1, recC, recP, nC, nP, blocksC);

    // 192 edges per block (48 edges/wave x 4 waves).
    edge_mlp<<<(nE + 191) / 192, 256, 0, stream>>>(
        recC, recP, src, dst, W1, W2, b2, out, nE);
}

// Round 4
// 139.344 us; speedup vs baseline: 1.1235x; 1.1235x over previous
//
#include <hip/hip_runtime.h>
#include <math.h>

// ---------------------------------------------------------------------------
// Cosine_PredictingModule v13.
//   cat@W1 = heads@W1a + tails@W1b + cos*W1[128]  (per-node precompute).
//   Node record (one 128-B line): [64 B fp8 hn | 64 B fp8 P(+b1 cust)].
//   K1 node_fused: v8 (all global traffic coalesced).
//   K2 edge_mlp v13: LDS-staged gathers via global_load_lds.
//      BUG FIX vs v11/v12: the builtin's `offset` arg applies to BOTH the
//      global AND the LDS address (LLVM IntrinsicsAMDGPU.td), so offset=64
//      shifted the LDS writes by 64 B -> every lane read the previous edge's
//      P bytes (absmax 0.67, identical across v11/v12 = deterministic).
//      Now: offset=0 everywhere, P-half global address computed explicitly.
//      2 batches x 16 edges/wave; all 8 staging instrs issued, then one
//      order-robust s_waitcnt vmcnt(0) drain. Gather depth costs LDS, not
//      VGPRs: 32 KB/block -> 5 blocks/CU -> 20 waves/CU; compute keeps the
//      lane-efficient 4-lanes/edge mapping.
// ---------------------------------------------------------------------------

typedef __attribute__((ext_vector_type(8))) short bf16x8;
typedef __attribute__((ext_vector_type(4))) float f32x4;
typedef __attribute__((ext_vector_type(2))) float float2_t;
typedef __attribute__((ext_vector_type(8))) unsigned short ushort8_t;
typedef __attribute__((ext_vector_type(4))) float float4_t;
typedef __attribute__((ext_vector_type(4))) unsigned int uint4_t;

#define T_STRIDE 72   // A-tile LDS stride (ushorts)
#define P_STRIDE 72   // acc-transpose LDS stride (ushorts)

__device__ __forceinline__ float bf2f(unsigned short u) {
    return __uint_as_float(((unsigned int)u) << 16);
}
__device__ __forceinline__ unsigned short f2bf(float f) {
    unsigned int x = __float_as_uint(f);
    return (unsigned short)((x + 0x7fffu + ((x >> 16) & 1u)) >> 16);
}

// K0: W1frag[half][nt][ks][lane][j] =
//   bf16(W1[half*64 + ks*32 + (lane>>4)*8 + j][nt*16 + (lane&15)])
__global__ __launch_bounds__(256) void prep_w1(
    const float* __restrict__ W1, unsigned short* __restrict__ frag)
{
    int idx = blockIdx.x * 256 + threadIdx.x;
    if (idx >= 2 * 4 * 2 * 64 * 8) return;
    int j    = idx & 7;
    int lane = (idx >> 3) & 63;
    int ks   = (idx >> 9) & 1;
    int nt   = (idx >> 10) & 3;
    int half = (idx >> 12) & 1;
    int k   = ks * 32 + (lane >> 4) * 8 + j;
    int col = nt * 16 + (lane & 15);
    frag[idx] = f2bf(W1[(half * 64 + k) * 64 + col]);
}

// K1 v8: 64 nodes/block, all global traffic coalesced.
__global__ __launch_bounds__(256) void node_fused(
    const float* __restrict__ hc, const float* __restrict__ hp,
    const unsigned short* __restrict__ w1frag, const float* __restrict__ b1,
    unsigned char* __restrict__ recC, unsigned char* __restrict__ recP,
    int nC, int nP, int blocksC)
{
    __shared__ unsigned short tileA[64 * T_STRIDE];
    __shared__ unsigned short tile2[64 * P_STRIDE];
    __shared__ unsigned char  recs[64 * 128];

    int b = blockIdx.x;
    const float* h; unsigned char* rec; int n, half;
    if (b < blocksC) { h = hc; rec = recC; n = nC; half = 0; }
    else { b -= blocksC; h = hp; rec = recP; n = nP; half = 1; }

    int node0 = b * 64;
    int nloc  = min(64, n - node0);
    int t     = threadIdx.x;
    int nl    = t >> 2, q = t & 3;
    int wave  = t >> 6, lane = t & 63;
    int m = lane & 15, quad = lane >> 4;

    if (nl < nloc) {
        const float* srcp = h + (long)(node0 + nl) * 64 + q * 16;
        float4_t v[4];
#pragma unroll
        for (int i = 0; i < 4; i++)
            v[i] = *reinterpret_cast<const float4_t*>(srcp + i * 4);

        float ss = 0.f;
#pragma unroll
        for (int i = 0; i < 4; i++)
#pragma unroll
            for (int j = 0; j < 4; j++) ss += v[i][j] * v[i][j];
        ss += __shfl_xor(ss, 1);
        ss += __shfl_xor(ss, 2);
        float inv = 1.f / fmaxf(sqrtf(ss), 1e-12f);

        ushort8_t u[2];
#pragma unroll
        for (int i = 0; i < 16; i++) u[i >> 3][i & 7] = f2bf(v[i >> 2][i & 3]);
        *reinterpret_cast<ushort8_t*>(&tileA[nl * T_STRIDE + q * 16])     = u[0];
        *reinterpret_cast<ushort8_t*>(&tileA[nl * T_STRIDE + q * 16 + 8]) = u[1];

        uint4_t u8;
#pragma unroll
        for (int i = 0; i < 4; i++) {
            unsigned int d = __builtin_amdgcn_cvt_pk_fp8_f32(
                v[i][0] * inv, v[i][1] * inv, 0, false);
            d = __builtin_amdgcn_cvt_pk_fp8_f32(
                v[i][2] * inv, v[i][3] * inv, d, true);
            u8[i] = d;
        }
        *reinterpret_cast<uint4_t*>(&recs[nl * 128 + q * 16]) = u8;
    }
    __syncthreads();

    if (wave * 16 < nloc) {
        bf16x8 a[2];
#pragma unroll
        for (int ks = 0; ks < 2; ks++)
            a[ks] = *reinterpret_cast<const bf16x8*>(
                &tileA[(wave * 16 + m) * T_STRIDE + ks * 32 + quad * 8]);

        f32x4 acc[4];
#pragma unroll
        for (int nt = 0; nt < 4; nt++) acc[nt] = (f32x4){0.f, 0.f, 0.f, 0.f};
#pragma unroll
        for (int nt = 0; nt < 4; nt++)
#pragma unroll
            for (int ks = 0; ks < 2; ks++) {
                bf16x8 bf = *reinterpret_cast<const bf16x8*>(
                    &w1frag[(((half * 4 + nt) * 2 + ks) * 64 + lane) * 8]);
                acc[nt] = __builtin_amdgcn_mfma_f32_16x16x32_bf16(
                    a[ks], bf, acc[nt], 0, 0, 0);
            }
        if (half == 0) {
#pragma unroll
            for (int nt = 0; nt < 4; nt++) {
                float bb = b1[nt * 16 + m];
#pragma unroll
                for (int r = 0; r < 4; r++) acc[nt][r] += bb;
            }
        }
#pragma unroll
        for (int nt = 0; nt < 4; nt++)
#pragma unroll
            for (int r = 0; r < 4; r++)
                tile2[(wave * 16 + quad * 4 + r) * P_STRIDE + nt * 16 + m]
                    = f2bf(acc[nt][r]);
    }
    __syncthreads();

    if (nl < nloc) {
        ushort8_t p0 = *reinterpret_cast<ushort8_t*>(&tile2[nl * P_STRIDE + q * 16]);
        ushort8_t p1 = *reinterpret_cast<ushort8_t*>(&tile2[nl * P_STRIDE + q * 16 + 8]);
        float v[16];
#pragma unroll
        for (int i = 0; i < 8; i++) { v[i] = bf2f(p0[i]); v[i + 8] = bf2f(p1[i]); }
        uint4_t u;
#pragma unroll
        for (int i = 0; i < 4; i++) {
            unsigned int d = __builtin_amdgcn_cvt_pk_fp8_f32(
                v[i * 4 + 0], v[i * 4 + 1], 0, false);
            d = __builtin_amdgcn_cvt_pk_fp8_f32(
                v[i * 4 + 2], v[i * 4 + 3], d, true);
            u[i] = d;
        }
        *reinterpret_cast<uint4_t*>(&recs[nl * 128 + 64 + q * 16]) = u;
    }
    __syncthreads();

    if (t * 32 < nloc * 128) {
        uint4_t r0 = *reinterpret_cast<uint4_t*>(&recs[t * 32]);
        uint4_t r1 = *reinterpret_cast<uint4_t*>(&recs[t * 32 + 16]);
        unsigned char* dstp = rec + (long)node0 * 128 + t * 32;
        *reinterpret_cast<uint4_t*>(dstp)      = r0;
        *reinterpret_cast<uint4_t*>(dstp + 16) = r1;
    }
}

// K2 v13: LDS-staged gathers. 4 lanes/edge, 16 edges/batch, 2 batches/wave.
// Granule layout per (wave,batch): [0]=hn_c [1]=P_c [2]=hn_p [3]=P_p, each
// 1 KB: lane l writes its 16-B chunk to granule + l*16 (HW: base + lane*16).
// offset arg is ALWAYS 0 (it shifts the LDS address too); P-half addresses
// are computed explicitly (+64 on the global pointer).
#define NB2 2
__global__ __launch_bounds__(256, 5) void edge_mlp(
    const unsigned char* __restrict__ recC, const unsigned char* __restrict__ recP,
    const int* __restrict__ src, const int* __restrict__ dst,
    const float* __restrict__ W1, const float* __restrict__ W2,
    const float* __restrict__ b2, float* __restrict__ out, int nE)
{
    __shared__ __attribute__((aligned(16))) unsigned char stage[4][NB2][4][1024]; // 32 KB

    int t    = threadIdx.x;
    int wave = t >> 6, lane = t & 63;
    int sub  = lane >> 2;      // edge slot within batch (0..15)
    int g    = lane & 3;       // 16-B chunk within a 64-B half
    int wid  = blockIdx.x * 4 + wave;
    int base = wid * (NB2 * 16);

    // L1-hot parameter loads.
    int d0 = g * 16;
    float4_t w1v[4], w2v[4];
#pragma unroll
    for (int i = 0; i < 4; i++) {
        w1v[i] = *reinterpret_cast<const float4_t*>(W1 + 128 * 64 + d0 + i * 4);
        w2v[i] = *reinterpret_cast<const float4_t*>(W2 + d0 + i * 4);
    }
    float b2v = b2[0];

    // Edge indices for both batches.
    int ed[NB2]; bool vd[NB2]; int sI[NB2], tI[NB2];
#pragma unroll
    for (int b = 0; b < NB2; b++) {
        ed[b] = base + b * 16 + sub;
        vd[b] = ed[b] < nE;
        int e = vd[b] ? ed[b] : 0;
        sI[b] = src[e];
        tI[b] = dst[e];
    }

    // Issue all 8 staging gathers (per-lane global addr -> linear LDS slot
    // granule + lane*16). offset=0 on every call.
#pragma unroll
    for (int b = 0; b < NB2; b++) {
        const unsigned char* csh = recC + (long)sI[b] * 128 + g * 16;       // hn_c
        const unsigned char* csp = csh + 64;                                 // P_c
        const unsigned char* cth = recP + (long)tI[b] * 128 + g * 16;       // hn_p
        const unsigned char* ctp = cth + 64;                                 // P_p
        __builtin_amdgcn_global_load_lds(
            (const unsigned int*)csh, (unsigned int*)&stage[wave][b][0][0], 16, 0, 0);
        __builtin_amdgcn_global_load_lds(
            (const unsigned int*)csp, (unsigned int*)&stage[wave][b][1][0], 16, 0, 0);
        __builtin_amdgcn_global_load_lds(
            (const unsigned int*)cth, (unsigned int*)&stage[wave][b][2][0], 16, 0, 0);
        __builtin_amdgcn_global_load_lds(
            (const unsigned int*)ctp, (unsigned int*)&stage[wave][b][3][0], 16, 0, 0);
    }

    // Single order-robust drain: all staging complete before any LDS read.
    asm volatile("s_waitcnt vmcnt(0)" ::: "memory");
    __builtin_amdgcn_sched_barrier(0);

    float res[NB2];
#pragma unroll
    for (int b = 0; b < NB2; b++) {
        uint4_t hs = *reinterpret_cast<const uint4_t*>(&stage[wave][b][0][lane * 16]);
        uint4_t ps = *reinterpret_cast<const uint4_t*>(&stage[wave][b][1][lane * 16]);
        uint4_t ht = *reinterpret_cast<const uint4_t*>(&stage[wave][b][2][lane * 16]);
        uint4_t pt = *reinterpret_cast<const uint4_t*>(&stage[wave][b][3][lane * 16]);

        // cosine partial dot (16 dims/lane).
        float dot = 0.f;
#pragma unroll
        for (int w = 0; w < 4; w++) {
            float2_t alo = __builtin_amdgcn_cvt_pk_f32_fp8((int)hs[w], false);
            float2_t ahi = __builtin_amdgcn_cvt_pk_f32_fp8((int)hs[w], true);
            float2_t blo = __builtin_amdgcn_cvt_pk_f32_fp8((int)ht[w], false);
            float2_t bhi = __builtin_amdgcn_cvt_pk_f32_fp8((int)ht[w], true);
            dot += alo[0] * blo[0] + alo[1] * blo[1] + ahi[0] * bhi[0] + ahi[1] * bhi[1];
        }
        dot += __shfl_xor(dot, 1);
        dot += __shfl_xor(dot, 2);
        float cosv = dot;                // denom folded (≈1 to 1e-7)

        // MLP partial (16 hidden dims/lane).
        float p = 0.f;
#pragma unroll
        for (int w = 0; w < 4; w++) {
            float2_t clo = __builtin_amdgcn_cvt_pk_f32_fp8((int)ps[w], false);
            float2_t chi = __builtin_amdgcn_cvt_pk_f32_fp8((int)ps[w], true);
            float2_t dlo = __builtin_amdgcn_cvt_pk_f32_fp8((int)pt[w], false);
            float2_t dhi = __builtin_amdgcn_cvt_pk_f32_fp8((int)pt[w], true);
            float pcv[4] = {clo[0], clo[1], chi[0], chi[1]};
            float ppv[4] = {dlo[0], dlo[1], dhi[0], dhi[1]};
#pragma unroll
            for (int j = 0; j < 4; j++) {
                float x = pcv[j] + ppv[j] + cosv * w1v[w][j];  // b1 folded
                x = fmaxf(x, 0.f);
                p += x * w2v[w][j];
            }
        }
        p += __shfl_xor(p, 1);
        p += __shfl_xor(p, 2);
        res[b] = p;
    }

#pragma unroll
    for (int b = 0; b < NB2; b++)
        if (vd[b] && g == 0)
            out[ed[b]] = 1.f / (1.f + expf(-(res[b] + b2v)));
}

extern "C" void kernel_launch(void* const* d_in, const int* in_sizes, int n_in,
                              void* d_out, int out_size, void* d_ws, size_t ws_size,
                              hipStream_t stream) {
    const float* h_c = (const float*)d_in[0];
    const float* h_p = (const float*)d_in[1];
    const int*   src = (const int*)d_in[2];
    const int*   dst = (const int*)d_in[3];
    const float* W1  = (const float*)d_in[4];
    const float* b1  = (const float*)d_in[5];
    const float* W2  = (const float*)d_in[6];
    const float* b2  = (const float*)d_in[7];
    float* out = (float*)d_out;

    int nC = in_sizes[0] / 64;
    int nP = in_sizes[1] / 64;
    int nE = in_sizes[2];

    char* ws = (char*)d_ws;
    size_t off = 0;
    auto carve = [&](size_t bytes) {
        void* p = ws + off;
        off = (off + bytes + 255) & ~(size_t)255;
        return p;
    };
    unsigned char* recC = (unsigned char*)carve((size_t)nC * 128);
    unsigned char* recP = (unsigned char*)carve((size_t)nP * 128);
    unsigned short* w1f = (unsigned short*)carve((size_t)16384 * 2);

    prep_w1<<<64, 256, 0, stream>>>(W1, w1f);

    int blocksC = (nC + 63) / 64, blocksP = (nP + 63) / 64;
    node_fused<<<blocksC + blocksP, 256, 0, stream>>>(
        h_c, h_p, w1f, b1, recC, recP, nC, nP, blocksC);

    // 128 edges per block (32 edges/wave x 4 waves).
    edge_mlp<<<(nE + 127) / 128, 256, 0, stream>>>(
        recC, recP, src, dst, W1, W2, b2, out, nE);
}